// Round 6
// baseline (1115.260 us; speedup 1.0000x reference)
//
#include <hip/hip_runtime.h>
#include <hip/hip_bf16.h>

// Problem constants (match reference)
#define B_GR   128
#define GWID   30
#define IWID   90
#define C_IN   32
#define R_REL  8
#define NBAS   4
#define N_NODES (B_GR*GWID*GWID)   // 115200
#define E_EDGES (N_NODES*8)        // 921600
#define NEG_SLOPE 0.01f

#define RN  (R_REL*N_NODES)        // 921600 (r,dst) bins
#define RB3 (RN/256)               // 3600 scan blocks

typedef __attribute__((ext_vector_type(8))) __bf16 bf16x8;
typedef __attribute__((ext_vector_type(4))) float f32x4;

// ======================================================================
// Weight prep: Wt[r][c][k] = bf16( sum_b comp[r,b]*bases[b,k,c] )   (B^T layout)
//              loopt[c][k] = bf16( loopw[k,c] )
// ======================================================================
__global__ void k_wcomp_t(const float* __restrict__ bases, const float* __restrict__ comp,
                          __bf16* __restrict__ Wt, int din, int dout) {
    int idx = blockIdx.x*256 + threadIdx.x;
    int tot = R_REL*din*dout;
    if (idx >= tot) return;
    int r = idx/(dout*din), rem = idx%(dout*din);
    int c = rem/din, k = rem%din;
    float acc = 0.f;
    #pragma unroll
    for (int b = 0; b < NBAS; ++b)
        acc += comp[r*NBAS + b]*bases[((size_t)b*din + k)*dout + c];
    Wt[idx] = (__bf16)acc;
}
__global__ void k_loop_t(const float* __restrict__ loopw, __bf16* __restrict__ loopt,
                         int din, int dout) {
    int idx = blockIdx.x*256 + threadIdx.x;
    if (idx >= din*dout) return;
    int c = idx/din, k = idx%din;
    loopt[idx] = (__bf16)loopw[(size_t)k*dout + c];
}

// ======================================================================
// prep: (relation, dst)-binned global CSR.  bin id = r*N + dst
// ======================================================================
__global__ void k_deg3(const int* __restrict__ dst, const int* __restrict__ et,
                       int* __restrict__ deg3) {
    int e = blockIdx.x*256 + threadIdx.x;
    if (e < E_EDGES) atomicAdd(&deg3[et[e]*N_NODES + dst[e]], 1);
}
// level-1 scan over RN elements (RB3 blocks of 256)
__global__ __launch_bounds__(256) void k_scan1(const int* __restrict__ deg,
                                               int* __restrict__ rowptr,
                                               int* __restrict__ bsum) {
    __shared__ int s[256], s2[256];
    const int tid = threadIdx.x, gid = blockIdx.x*256 + tid;
    int v = deg[gid];
    s[tid] = v;
    __syncthreads();
    int* cur = s; int* nxt = s2;
    for (int d = 1; d < 256; d <<= 1) {
        int val = cur[tid];
        if (tid >= d) val += cur[tid - d];
        nxt[tid] = val;
        __syncthreads();
        int* t = cur; cur = nxt; nxt = t;
    }
    rowptr[gid] = cur[tid] - v;
    if (tid == 255) bsum[blockIdx.x] = cur[255];
}
// level-2: one block, 1024 threads, scans RB3=3600 block sums (4 per thread)
__global__ __launch_bounds__(1024) void k_scan2b(int* __restrict__ bsum) {
    __shared__ int s[1024], s2[1024];
    const int tid = threadIdx.x;
    int v[4]; int loc = 0;
    #pragma unroll
    for (int i = 0; i < 4; ++i) {
        int idx = tid*4 + i;
        v[i] = (idx < RB3) ? bsum[idx] : 0;
        loc += v[i];
    }
    s[tid] = loc;
    __syncthreads();
    int* cur = s; int* nxt = s2;
    for (int d = 1; d < 1024; d <<= 1) {
        int val = cur[tid];
        if (tid >= d) val += cur[tid - d];
        nxt[tid] = val;
        __syncthreads();
        int* t = cur; cur = nxt; nxt = t;
    }
    int run = cur[tid] - loc;   // exclusive across threads
    #pragma unroll
    for (int i = 0; i < 4; ++i) {
        int idx = tid*4 + i;
        if (idx < RB3) bsum[idx] = run;
        run += v[i];
    }
}
// level-3 add-back; also seed cursor
__global__ void k_scan3b(int* __restrict__ rowptr, const int* __restrict__ bsum,
                         int* __restrict__ cursor) {
    int gid = blockIdx.x*256 + threadIdx.x;
    int v = rowptr[gid] + bsum[blockIdx.x];
    rowptr[gid] = v;
    cursor[gid] = v;
}
__global__ void k_cap(int* __restrict__ rowptr) {
    if (threadIdx.x == 0 && blockIdx.x == 0) rowptr[RN] = E_EDGES;
}
// direct scatter into final (r,dst)-sorted slots
__global__ void k_scatter3(const int* __restrict__ src, const int* __restrict__ dst,
                           const int* __restrict__ et, const float* __restrict__ norm,
                           int* __restrict__ cursor, int* __restrict__ pidx2,
                           float* __restrict__ pnorm2, int* __restrict__ pdst) {
    int e = blockIdx.x*256 + threadIdx.x;
    if (e < E_EDGES) {
        int pos = atomicAdd(&cursor[et[e]*N_NODES + dst[e]], 1);
        pidx2[pos]  = src[e];
        pnorm2[pos] = norm[e];
        pdst[pos]   = dst[e];
    }
}

// ======================================================================
// Fused RGCN layer, edge-parallel LDS build + MFMA:
//   hout[n] = act( sum_r (sum_{e in in(n),et=r} norm*h[src]) @ W_r + h[n]@loopw + bias )
// Block = 256 threads = 4 waves, owns 64 dst rows.
// Per relation r: zero 64xDIN f32 LDS tile; 4 threads/edge gather-accumulate
// (ds_add_f32); barrier; each wave MFMAs its 16 rows (A from LDS, B=Wt[r] L1-hot).
// Self-loop phase reads h[node] straight to registers (no LDS).
// A-frag: lane(m=l&15,g=l>>4) row m, cols ks*32+g*8..+7. D: row g*4+ri, col nf*16+m.
// ======================================================================
template<int DIN, int DOUT, int ACT, int IN_F32>
__global__ __launch_bounds__(256) void k_fused_lds(
        const void* __restrict__ hin, const __bf16* __restrict__ Wt,
        const __bf16* __restrict__ loopt, const float* __restrict__ bias,
        const int* __restrict__ rowptr3, const int* __restrict__ pidx2,
        const float* __restrict__ pnorm2, const int* __restrict__ pdst,
        __bf16* __restrict__ hout) {
    constexpr int STRIDE = DIN + 4;      // f32 words/row: 68 or 36 (2-way bank alias = free)
    __shared__ float As[64*STRIDE];
    constexpr int KS = DIN/32;
    constexpr int NF = DOUT/16;
    constexpr int CPT = DIN/4;           // cols per quarter-thread
    const int tid = threadIdx.x;
    const int w = tid >> 6, l = tid & 63;
    const int m = l & 15, g = l >> 4;
    const int node0 = blockIdx.x*64;     // block's 64 dst rows
    const int nb = node0 + w*16;         // wave's 16 rows
    const int q = tid & 3;

    f32x4 acc[NF];
    #pragma unroll
    for (int nf = 0; nf < NF; ++nf) acc[nf] = (f32x4){0.f,0.f,0.f,0.f};

    for (int r = 0; r < R_REL; ++r) {
        __syncthreads();   // As reads from previous phase done
        // ---- zero tile ----
        for (int i = tid; i < 64*STRIDE/4; i += 256)
            reinterpret_cast<float4*>(As)[i] = make_float4(0.f,0.f,0.f,0.f);
        __syncthreads();
        // ---- edge-parallel build: 4 threads per slot ----
        const int jb = rowptr3[r*N_NODES + node0];
        const int je = rowptr3[r*N_NODES + node0 + 64];
        for (int j = jb + (tid >> 2); j < je; j += 64) {
            const int   p  = pidx2[j];
            const float nm = pnorm2[j];
            const int   dl = pdst[j] - node0;
            float* dp = &As[dl*STRIDE + q*CPT];
            if (IN_F32) {
                const float* hp = (const float*)hin + (size_t)p*DIN + q*CPT;
                #pragma unroll
                for (int c4 = 0; c4 < CPT/4; ++c4) {
                    float4 v = *(const float4*)(hp + c4*4);
                    atomicAdd(&dp[c4*4+0], nm*v.x);
                    atomicAdd(&dp[c4*4+1], nm*v.y);
                    atomicAdd(&dp[c4*4+2], nm*v.z);
                    atomicAdd(&dp[c4*4+3], nm*v.w);
                }
            } else {
                const __bf16* hp = (const __bf16*)hin + (size_t)p*DIN + q*CPT;
                #pragma unroll
                for (int c8 = 0; c8 < CPT/8; ++c8) {
                    bf16x8 v = *(const bf16x8*)(hp + c8*8);
                    #pragma unroll
                    for (int jj = 0; jj < 8; ++jj)
                        atomicAdd(&dp[c8*8+jj], nm*(float)v[jj]);
                }
            }
        }
        __syncthreads();
        // ---- MFMA from LDS tile ----
        #pragma unroll
        for (int ks = 0; ks < KS; ++ks) {
            const float* ap = &As[(w*16 + m)*STRIDE + ks*32 + g*8];
            float4 a0 = *(const float4*)ap;
            float4 a1 = *(const float4*)(ap + 4);
            bf16x8 fa;
            fa[0]=(__bf16)a0.x; fa[1]=(__bf16)a0.y; fa[2]=(__bf16)a0.z; fa[3]=(__bf16)a0.w;
            fa[4]=(__bf16)a1.x; fa[5]=(__bf16)a1.y; fa[6]=(__bf16)a1.z; fa[7]=(__bf16)a1.w;
            #pragma unroll
            for (int nf = 0; nf < NF; ++nf) {
                bf16x8 fb = *(const bf16x8*)(Wt + (size_t)r*DOUT*DIN
                                             + (size_t)(nf*16 + m)*DIN + ks*32 + g*8);
                acc[nf] = __builtin_amdgcn_mfma_f32_16x16x32_bf16(fa, fb, acc[nf], 0, 0, 0);
            }
        }
    }

    // ---- self-loop phase: A row = h[nb+m], register-direct ----
    #pragma unroll
    for (int ks = 0; ks < KS; ++ks) {
        bf16x8 fa;
        if (IN_F32) {
            const float* hp = (const float*)hin + (size_t)(nb + m)*DIN + ks*32 + g*8;
            float4 v0 = *(const float4*)hp;
            float4 v1 = *(const float4*)(hp + 4);
            fa[0]=(__bf16)v0.x; fa[1]=(__bf16)v0.y; fa[2]=(__bf16)v0.z; fa[3]=(__bf16)v0.w;
            fa[4]=(__bf16)v1.x; fa[5]=(__bf16)v1.y; fa[6]=(__bf16)v1.z; fa[7]=(__bf16)v1.w;
        } else {
            fa = *(const bf16x8*)((const __bf16*)hin + (size_t)(nb + m)*DIN + ks*32 + g*8);
        }
        #pragma unroll
        for (int nf = 0; nf < NF; ++nf) {
            bf16x8 fb = *(const bf16x8*)(loopt + (size_t)(nf*16 + m)*DIN + ks*32 + g*8);
            acc[nf] = __builtin_amdgcn_mfma_f32_16x16x32_bf16(fa, fb, acc[nf], 0, 0, 0);
        }
    }

    // ---- epilogue: bias + activation + bf16 store ----
    #pragma unroll
    for (int nf = 0; nf < NF; ++nf) {
        const int col = nf*16 + m;
        const float bv = bias[col];
        #pragma unroll
        for (int ri = 0; ri < 4; ++ri) {
            const int orow = nb + g*4 + ri;
            float v = acc[nf][ri] + bv;
            if (ACT == 0) v = (v >= 0.f) ? v : NEG_SLOPE*v;
            else          v = 1.f/(1.f + __expf(-v));
            hout[(size_t)orow*DOUT + col] = (__bf16)v;
        }
    }
}

// ======================================================================
// conv-transpose decoder + sigmoid (bf16 logits input)
// ======================================================================
__global__ __launch_bounds__(256) void k_convt(const __bf16* __restrict__ logits,
        const float* __restrict__ w, const float* __restrict__ cb, float* __restrict__ out) {
    __shared__ float s_w[49*32];
    const int tid = threadIdx.x;
    for (int idx = tid; idx < 49*32; idx += 256) {
        int tap = idx/32, c = idx%32;
        s_w[tap*32 + c] = w[c*49 + tap];
    }
    __syncthreads();
    int gidx = blockIdx.x*256 + tid;
    if (gidx >= B_GR*IWID*IWID) return;
    int b = gidx/(IWID*IWID);
    int rem = gidx%(IWID*IWID);
    int oy = rem/IWID, ox = rem%IWID;

    float acc = cb[0];
    for (int ky = 0; ky < 7; ++ky) {
        int t = oy + 2 - ky;
        if (t < 0 || (t % 3) != 0) continue;
        int iy = t/3; if (iy >= GWID) continue;
        for (int kx = 0; kx < 7; ++kx) {
            int u = ox + 2 - kx;
            if (u < 0 || (u % 3) != 0) continue;
            int ix = u/3; if (ix >= GWID) continue;
            const bf16x8* xp = (const bf16x8*)&logits[(((size_t)b*GWID + iy)*GWID + ix)*32];
            const float* wp = &s_w[(ky*7 + kx)*32];
            #pragma unroll
            for (int c8 = 0; c8 < 4; ++c8) {
                bf16x8 xv = xp[c8];
                #pragma unroll
                for (int jj = 0; jj < 8; ++jj)
                    acc += (float)xv[jj]*wp[c8*8 + jj];
            }
        }
    }
    out[gidx] = 1.f/(1.f + __expf(-acc));
}

// ======================================================================
// host
// ======================================================================
extern "C" void kernel_launch(void* const* d_in, const int* in_sizes, int n_in,
                              void* d_out, int out_size, void* d_ws, size_t ws_size,
                              hipStream_t stream) {
    const float* features = (const float*)d_in[0];
    const int*   src      = (const int*)  d_in[1];
    const int*   dst      = (const int*)  d_in[2];
    const int*   etypes   = (const int*)  d_in[3];
    const float* norm     = (const float*)d_in[4];
    const float* bases0 = (const float*)d_in[5];
    const float* comp0  = (const float*)d_in[6];
    const float* loop0  = (const float*)d_in[7];
    const float* bias0  = (const float*)d_in[8];
    const float* bases1 = (const float*)d_in[9];
    const float* comp1  = (const float*)d_in[10];
    const float* loop1  = (const float*)d_in[11];
    const float* bias1  = (const float*)d_in[12];
    const float* bases2 = (const float*)d_in[13];
    const float* comp2  = (const float*)d_in[14];
    const float* loop2  = (const float*)d_in[15];
    const float* bias2  = (const float*)d_in[16];
    const float* conv_w = (const float*)d_in[17];
    const float* conv_b = (const float*)d_in[18];
    float* out = (float*)d_out;

    // ---- workspace carve-up (float units), total ~59 MB ----
    float* ws = (float*)d_ws;
    size_t off = 0;
    __bf16* Wt0   = (__bf16*)(ws + off); off += (size_t)R_REL*64*32/2;
    __bf16* Wt1   = (__bf16*)(ws + off); off += (size_t)R_REL*64*64/2;
    __bf16* Wt2   = (__bf16*)(ws + off); off += (size_t)R_REL*32*64/2;
    __bf16* lt0   = (__bf16*)(ws + off); off += (size_t)64*32/2;
    __bf16* lt1   = (__bf16*)(ws + off); off += (size_t)64*64/2;
    __bf16* lt2   = (__bf16*)(ws + off); off += (size_t)32*64/2;
    __bf16* h1    = (__bf16*)(ws + off); off += (size_t)N_NODES*64/2;
    __bf16* h2    = (__bf16*)(ws + off); off += (size_t)N_NODES*64/2;
    __bf16* lg    = (__bf16*)(ws + off); off += (size_t)N_NODES*32/2;
    int* rowptr3  = (int*)(ws + off); off += (size_t)RN + 4;
    int* cursor3  = (int*)(ws + off); off += (size_t)RN;
    int* deg3     = (int*)(ws + off); off += (size_t)RN;
    int* bsum     = (int*)(ws + off); off += 4096;
    int* pidx2    = (int*)(ws + off); off += (size_t)E_EDGES;
    float* pnorm2 = ws + off;          off += (size_t)E_EDGES;
    int* pdst     = (int*)(ws + off);  off += (size_t)E_EDGES;

    const int ebl = (E_EDGES + 255)/256;

    // ---- weight prep (transposed bf16) ----
    k_wcomp_t<<<(R_REL*32*64 + 255)/256, 256, 0, stream>>>(bases0, comp0, Wt0, 32, 64);
    k_wcomp_t<<<(R_REL*64*64 + 255)/256, 256, 0, stream>>>(bases1, comp1, Wt1, 64, 64);
    k_wcomp_t<<<(R_REL*64*32 + 255)/256, 256, 0, stream>>>(bases2, comp2, Wt2, 64, 32);
    k_loop_t<<<(32*64 + 255)/256, 256, 0, stream>>>(loop0, lt0, 32, 64);
    k_loop_t<<<(64*64 + 255)/256, 256, 0, stream>>>(loop1, lt1, 64, 64);
    k_loop_t<<<(64*32 + 255)/256, 256, 0, stream>>>(loop2, lt2, 64, 32);

    // ---- (relation,dst)-binned global CSR (reused by all 3 layers) ----
    hipMemsetAsync(deg3, 0, (size_t)RN*sizeof(int), stream);
    k_deg3    <<<ebl, 256, 0, stream>>>(dst, etypes, deg3);
    k_scan1   <<<RB3, 256, 0, stream>>>(deg3, rowptr3, bsum);
    k_scan2b  <<<1, 1024, 0, stream>>>(bsum);
    k_scan3b  <<<RB3, 256, 0, stream>>>(rowptr3, bsum, cursor3);
    k_cap     <<<1, 64, 0, stream>>>(rowptr3);
    k_scatter3<<<ebl, 256, 0, stream>>>(src, dst, etypes, norm, cursor3,
                                        pidx2, pnorm2, pdst);

    const int NROWT = N_NODES/64;   // 1800

    // ---- 3 fused layers ----
    k_fused_lds<32,64,0,1><<<NROWT, 256, 0, stream>>>(features, Wt0, lt0, bias0,
                                                      rowptr3, pidx2, pnorm2, pdst, h1);
    k_fused_lds<64,64,0,0><<<NROWT, 256, 0, stream>>>(h1, Wt1, lt1, bias1,
                                                      rowptr3, pidx2, pnorm2, pdst, h2);
    k_fused_lds<64,32,1,0><<<NROWT, 256, 0, stream>>>(h2, Wt2, lt2, bias2,
                                                      rowptr3, pidx2, pnorm2, pdst, lg);

    // ---- decoder ----
    k_convt<<<(B_GR*IWID*IWID + 255)/256, 256, 0, stream>>>(lg, conv_w, conv_b, out);
}

// Round 7
// 519.669 us; speedup vs baseline: 2.1461x; 2.1461x over previous
//
#include <hip/hip_runtime.h>
#include <hip/hip_bf16.h>

// Problem constants (match reference)
#define B_GR   128
#define GWID   30
#define IWID   90
#define C_IN   32
#define R_REL  8
#define NBAS   4
#define N_NODES (B_GR*GWID*GWID)   // 115200
#define E_EDGES (N_NODES*8)        // 921600
#define NEG_SLOPE 0.01f

#define SCAN_BLOCKS (N_NODES/256)  // 450

typedef __attribute__((ext_vector_type(8))) __bf16 bf16x8;
typedef __attribute__((ext_vector_type(4))) float f32x4;

// ======================================================================
// Weight prep: Wt[r][c][k] = bf16( sum_b comp[r,b]*bases[b,k,c] )   (B^T layout)
//              loopt[c][k] = bf16( loopw[k,c] )
// ======================================================================
__global__ void k_wcomp_t(const float* __restrict__ bases, const float* __restrict__ comp,
                          __bf16* __restrict__ Wt, int din, int dout) {
    int idx = blockIdx.x*256 + threadIdx.x;
    int tot = R_REL*din*dout;
    if (idx >= tot) return;
    int r = idx/(dout*din), rem = idx%(dout*din);
    int c = rem/din, k = rem%din;
    float acc = 0.f;
    #pragma unroll
    for (int b = 0; b < NBAS; ++b)
        acc += comp[r*NBAS + b]*bases[((size_t)b*din + k)*dout + c];
    Wt[idx] = (__bf16)acc;
}
__global__ void k_loop_t(const float* __restrict__ loopw, __bf16* __restrict__ loopt,
                         int din, int dout) {
    int idx = blockIdx.x*256 + threadIdx.x;
    if (idx >= din*dout) return;
    int c = idx/din, k = idx%din;
    loopt[idx] = (__bf16)loopw[(size_t)k*dout + c];
}

// ======================================================================
// prep: (dst, etype)-binned CSR (dst-major). Reused by all 3 layers.
// ======================================================================
__global__ void k_deg2(const int* __restrict__ dst, const int* __restrict__ et,
                       int* __restrict__ deg2) {
    int e = blockIdx.x*256 + threadIdx.x;
    if (e < E_EDGES) atomicAdd(&deg2[dst[e]*R_REL + et[e]], 1);
}
__global__ void k_degsum(const int* __restrict__ deg2, int* __restrict__ deg) {
    int n = blockIdx.x*256 + threadIdx.x;
    if (n >= N_NODES) return;
    int s = 0;
    #pragma unroll
    for (int r = 0; r < R_REL; ++r) s += deg2[n*R_REL + r];
    deg[n] = s;
}
__global__ __launch_bounds__(256) void k_scan1(const int* __restrict__ deg,
                                               int* __restrict__ rowptr,
                                               int* __restrict__ bsum) {
    __shared__ int s[256], s2[256];
    const int tid = threadIdx.x, gid = blockIdx.x*256 + tid;
    int v = deg[gid];
    s[tid] = v;
    __syncthreads();
    int* cur = s; int* nxt = s2;
    for (int d = 1; d < 256; d <<= 1) {
        int val = cur[tid];
        if (tid >= d) val += cur[tid - d];
        nxt[tid] = val;
        __syncthreads();
        int* t = cur; cur = nxt; nxt = t;
    }
    rowptr[gid] = cur[tid] - v;
    if (tid == 255) bsum[blockIdx.x] = cur[255];
}
__global__ __launch_bounds__(512) void k_scan2(int* __restrict__ bsum, int* __restrict__ rowptr) {
    __shared__ int s[512], s2[512];
    const int tid = threadIdx.x;
    int v = (tid < SCAN_BLOCKS) ? bsum[tid] : 0;
    s[tid] = v;
    __syncthreads();
    int* cur = s; int* nxt = s2;
    for (int d = 1; d < 512; d <<= 1) {
        int val = cur[tid];
        if (tid >= d) val += cur[tid - d];
        nxt[tid] = val;
        __syncthreads();
        int* t = cur; cur = nxt; nxt = t;
    }
    if (tid < SCAN_BLOCKS) bsum[tid] = cur[tid] - v;   // exclusive
    if (tid == 0) rowptr[N_NODES] = E_EDGES;
}
__global__ void k_scan3(int* __restrict__ rowptr, const int* __restrict__ bsum) {
    int gid = blockIdx.x*256 + threadIdx.x;
    rowptr[gid] = rowptr[gid] + bsum[blockIdx.x];
}
__global__ void k_rowptr2(const int* __restrict__ rowptr, const int* __restrict__ deg2,
                          int* __restrict__ rowptr2, int* __restrict__ cursor2) {
    int n = blockIdx.x*256 + threadIdx.x;
    if (n >= N_NODES) return;
    int base = rowptr[n];
    #pragma unroll
    for (int r = 0; r < R_REL; ++r) {
        rowptr2[n*9 + r] = base;
        cursor2[n*R_REL + r] = base;
        base += deg2[n*R_REL + r];
    }
    rowptr2[n*9 + 8] = base;
}
__global__ void k_scatter_direct(const int* __restrict__ src, const int* __restrict__ dst,
                                 const int* __restrict__ et, const float* __restrict__ norm,
                                 int* __restrict__ cursor2, int* __restrict__ pidx2,
                                 float* __restrict__ pnorm2) {
    int e = blockIdx.x*256 + threadIdx.x;
    if (e < E_EDGES) {
        int pos = atomicAdd(&cursor2[dst[e]*R_REL + et[e]], 1);
        pidx2[pos]  = src[e];
        pnorm2[pos] = norm[e];
    }
}

// ======================================================================
// Pass A: aggregation.  x[n][r*DIN + c] = sum_{e in in(n),et=r} norm*h[src][c]
// 4 threads per node, CPT = DIN/4 cols each. f32 reg accumulate -> bf16 store.
// Pure gather kernel: 460K threads, independent loads, no LDS, no MFMA.
// ======================================================================
template<int DIN, int IN_F32>
__global__ __launch_bounds__(256) void k_agg(
        const void* __restrict__ hin, const int* __restrict__ rowptr2,
        const int* __restrict__ pidx2, const float* __restrict__ pnorm2,
        __bf16* __restrict__ xout) {
    constexpr int CPT = DIN/4;           // 16 (DIN=64) or 8 (DIN=32)
    const int t = blockIdx.x*256 + threadIdx.x;
    const int n = t >> 2, q = t & 3;
    const int c0 = q*CPT;
    int ptr[9];
    #pragma unroll
    for (int r = 0; r < 9; ++r) ptr[r] = rowptr2[n*9 + r];

    __bf16* xrow = xout + (size_t)n*(R_REL*DIN) + c0;
    #pragma unroll
    for (int r = 0; r < R_REL; ++r) {
        float a[CPT];
        #pragma unroll
        for (int c = 0; c < CPT; ++c) a[c] = 0.f;
        for (int j = ptr[r]; j < ptr[r+1]; ++j) {
            const int p = pidx2[j];
            const float nm = pnorm2[j];
            if (IN_F32) {
                const float* hp = (const float*)hin + (size_t)p*DIN + c0;
                #pragma unroll
                for (int c4 = 0; c4 < CPT/4; ++c4) {
                    float4 v = *(const float4*)(hp + c4*4);
                    a[c4*4+0] += nm*v.x; a[c4*4+1] += nm*v.y;
                    a[c4*4+2] += nm*v.z; a[c4*4+3] += nm*v.w;
                }
            } else {
                const __bf16* hp = (const __bf16*)hin + (size_t)p*DIN + c0;
                #pragma unroll
                for (int c8 = 0; c8 < CPT/8; ++c8) {
                    bf16x8 v = *(const bf16x8*)(hp + c8*8);
                    #pragma unroll
                    for (int jj = 0; jj < 8; ++jj) a[c8*8+jj] += nm*(float)v[jj];
                }
            }
        }
        // store bf16 slice
        #pragma unroll
        for (int c8 = 0; c8 < CPT/8; ++c8) {
            bf16x8 o;
            #pragma unroll
            for (int jj = 0; jj < 8; ++jj) o[jj] = (__bf16)a[c8*8+jj];
            *(bf16x8*)(xrow + (size_t)r*DIN + c8*8) = o;
        }
    }
}

// ======================================================================
// Pass B: grouped GEMM.  hout[n] = act( x[n] @ Wstack + h[n] @ loopw + bias )
// Wave owns 16 rows; streaming A-reads from x; B from L1-hot weight tables.
// Lane l: m=l&15, g=l>>4. A-frag: row nb+m, cols ks*32+g*8. D: row=nb+g*4+ri,
// col=nf*16+m (m89-verified).
// ======================================================================
template<int DIN, int DOUT, int ACT, int IN_F32>
__global__ __launch_bounds__(256) void k_ggemm(
        const __bf16* __restrict__ x, const void* __restrict__ hin,
        const __bf16* __restrict__ Wt, const __bf16* __restrict__ loopt,
        const float* __restrict__ bias, __bf16* __restrict__ hout) {
    constexpr int KS = DIN/32;
    constexpr int NF = DOUT/16;
    const int tid = threadIdx.x;
    const int w = tid >> 6, l = tid & 63;
    const int m = l & 15, g = l >> 4;
    const int nb = blockIdx.x*64 + w*16;

    f32x4 acc[NF];
    #pragma unroll
    for (int nf = 0; nf < NF; ++nf) acc[nf] = (f32x4){0.f,0.f,0.f,0.f};

    const __bf16* xrow = x + (size_t)(nb + m)*(R_REL*DIN);
    #pragma unroll
    for (int r = 0; r < R_REL; ++r) {
        #pragma unroll
        for (int ks = 0; ks < KS; ++ks) {
            bf16x8 fa = *(const bf16x8*)(xrow + r*DIN + ks*32 + g*8);
            #pragma unroll
            for (int nf = 0; nf < NF; ++nf) {
                bf16x8 fb = *(const bf16x8*)(Wt + (size_t)r*DOUT*DIN
                                             + (size_t)(nf*16 + m)*DIN + ks*32 + g*8);
                acc[nf] = __builtin_amdgcn_mfma_f32_16x16x32_bf16(fa, fb, acc[nf], 0, 0, 0);
            }
        }
    }
    // self-loop
    #pragma unroll
    for (int ks = 0; ks < KS; ++ks) {
        bf16x8 fa;
        if (IN_F32) {
            const float* hp = (const float*)hin + (size_t)(nb + m)*DIN + ks*32 + g*8;
            float4 v0 = *(const float4*)hp;
            float4 v1 = *(const float4*)(hp + 4);
            fa[0]=(__bf16)v0.x; fa[1]=(__bf16)v0.y; fa[2]=(__bf16)v0.z; fa[3]=(__bf16)v0.w;
            fa[4]=(__bf16)v1.x; fa[5]=(__bf16)v1.y; fa[6]=(__bf16)v1.z; fa[7]=(__bf16)v1.w;
        } else {
            fa = *(const bf16x8*)((const __bf16*)hin + (size_t)(nb + m)*DIN + ks*32 + g*8);
        }
        #pragma unroll
        for (int nf = 0; nf < NF; ++nf) {
            bf16x8 fb = *(const bf16x8*)(loopt + (size_t)(nf*16 + m)*DIN + ks*32 + g*8);
            acc[nf] = __builtin_amdgcn_mfma_f32_16x16x32_bf16(fa, fb, acc[nf], 0, 0, 0);
        }
    }
    // epilogue
    #pragma unroll
    for (int nf = 0; nf < NF; ++nf) {
        const int col = nf*16 + m;
        const float bv = bias[col];
        #pragma unroll
        for (int ri = 0; ri < 4; ++ri) {
            const int orow = nb + g*4 + ri;
            float v = acc[nf][ri] + bv;
            if (ACT == 0) v = (v >= 0.f) ? v : NEG_SLOPE*v;
            else          v = 1.f/(1.f + __expf(-v));
            hout[(size_t)orow*DOUT + col] = (__bf16)v;
        }
    }
}

// ======================================================================
// FALLBACK: round-5 fused kernel (per-lane gather, 439 µs total path)
// ======================================================================
template<int DIN, int DOUT, int ACT, int IN_F32>
__global__ __launch_bounds__(256) void k_fused_mfma(
        const void* __restrict__ hin, const __bf16* __restrict__ Wt,
        const __bf16* __restrict__ loopt, const float* __restrict__ bias,
        const int* __restrict__ rowptr2, const int* __restrict__ pidx2,
        const float* __restrict__ pnorm2, __bf16* __restrict__ hout) {
    constexpr int KS = DIN/32;
    constexpr int NF = DOUT/16;
    const int tid = threadIdx.x;
    const int w = tid >> 6;
    const int l = tid & 63;
    const int m = l & 15, g = l >> 4;
    const int node0 = blockIdx.x*64 + w*16;
    const int node = node0 + m;

    f32x4 acc[NF];
    #pragma unroll
    for (int nf = 0; nf < NF; ++nf) acc[nf] = (f32x4){0.f,0.f,0.f,0.f};

    for (int r = 0; r < 9; ++r) {
        float ka[KS][8];
        #pragma unroll
        for (int ks = 0; ks < KS; ++ks)
            #pragma unroll
            for (int j = 0; j < 8; ++j) ka[ks][j] = 0.f;

        if (r < R_REL) {
            const int jb = rowptr2[node*9 + r];
            const int je = rowptr2[node*9 + r + 1];
            for (int j = jb; j < je; ++j) {
                const int p = pidx2[j];
                const float nm = pnorm2[j];
                if (IN_F32) {
                    const float* hp = (const float*)hin + (size_t)p*DIN + g*8;
                    #pragma unroll
                    for (int ks = 0; ks < KS; ++ks) {
                        float4 v0 = *(const float4*)(hp + ks*32);
                        float4 v1 = *(const float4*)(hp + ks*32 + 4);
                        ka[ks][0] += nm*v0.x; ka[ks][1] += nm*v0.y;
                        ka[ks][2] += nm*v0.z; ka[ks][3] += nm*v0.w;
                        ka[ks][4] += nm*v1.x; ka[ks][5] += nm*v1.y;
                        ka[ks][6] += nm*v1.z; ka[ks][7] += nm*v1.w;
                    }
                } else {
                    const __bf16* hp = (const __bf16*)hin + (size_t)p*DIN + g*8;
                    #pragma unroll
                    for (int ks = 0; ks < KS; ++ks) {
                        bf16x8 v = *(const bf16x8*)(hp + ks*32);
                        #pragma unroll
                        for (int jj = 0; jj < 8; ++jj) ka[ks][jj] += nm*(float)v[jj];
                    }
                }
            }
        } else {
            if (IN_F32) {
                const float* hp = (const float*)hin + (size_t)node*DIN + g*8;
                #pragma unroll
                for (int ks = 0; ks < KS; ++ks) {
                    float4 v0 = *(const float4*)(hp + ks*32);
                    float4 v1 = *(const float4*)(hp + ks*32 + 4);
                    ka[ks][0] = v0.x; ka[ks][1] = v0.y; ka[ks][2] = v0.z; ka[ks][3] = v0.w;
                    ka[ks][4] = v1.x; ka[ks][5] = v1.y; ka[ks][6] = v1.z; ka[ks][7] = v1.w;
                }
            } else {
                const __bf16* hp = (const __bf16*)hin + (size_t)node*DIN + g*8;
                #pragma unroll
                for (int ks = 0; ks < KS; ++ks) {
                    bf16x8 v = *(const bf16x8*)(hp + ks*32);
                    #pragma unroll
                    for (int jj = 0; jj < 8; ++jj) ka[ks][jj] = (float)v[jj];
                }
            }
        }

        bf16x8 fa[KS];
        #pragma unroll
        for (int ks = 0; ks < KS; ++ks)
            #pragma unroll
            for (int jj = 0; jj < 8; ++jj) fa[ks][jj] = (__bf16)ka[ks][jj];

        const __bf16* Bt = (r < R_REL) ? (Wt + (size_t)r*DOUT*DIN) : loopt;
        #pragma unroll
        for (int ks = 0; ks < KS; ++ks) {
            #pragma unroll
            for (int nf = 0; nf < NF; ++nf) {
                bf16x8 fb = *(const bf16x8*)(Bt + (size_t)(nf*16 + m)*DIN + ks*32 + g*8);
                acc[nf] = __builtin_amdgcn_mfma_f32_16x16x32_bf16(fa[ks], fb, acc[nf], 0, 0, 0);
            }
        }
    }
    #pragma unroll
    for (int nf = 0; nf < NF; ++nf) {
        const int col = nf*16 + m;
        const float bv = bias[col];
        #pragma unroll
        for (int ri = 0; ri < 4; ++ri) {
            const int orow = node0 + g*4 + ri;
            float v = acc[nf][ri] + bv;
            if (ACT == 0) v = (v >= 0.f) ? v : NEG_SLOPE*v;
            else          v = 1.f/(1.f + __expf(-v));
            hout[(size_t)orow*DOUT + col] = (__bf16)v;
        }
    }
}

// ======================================================================
// conv-transpose decoder + sigmoid (bf16 logits input)
// ======================================================================
__global__ __launch_bounds__(256) void k_convt(const __bf16* __restrict__ logits,
        const float* __restrict__ w, const float* __restrict__ cb, float* __restrict__ out) {
    __shared__ float s_w[49*32];
    const int tid = threadIdx.x;
    for (int idx = tid; idx < 49*32; idx += 256) {
        int tap = idx/32, c = idx%32;
        s_w[tap*32 + c] = w[c*49 + tap];
    }
    __syncthreads();
    int gidx = blockIdx.x*256 + tid;
    if (gidx >= B_GR*IWID*IWID) return;
    int b = gidx/(IWID*IWID);
    int rem = gidx%(IWID*IWID);
    int oy = rem/IWID, ox = rem%IWID;

    float acc = cb[0];
    for (int ky = 0; ky < 7; ++ky) {
        int t = oy + 2 - ky;
        if (t < 0 || (t % 3) != 0) continue;
        int iy = t/3; if (iy >= GWID) continue;
        for (int kx = 0; kx < 7; ++kx) {
            int u = ox + 2 - kx;
            if (u < 0 || (u % 3) != 0) continue;
            int ix = u/3; if (ix >= GWID) continue;
            const bf16x8* xp = (const bf16x8*)&logits[(((size_t)b*GWID + iy)*GWID + ix)*32];
            const float* wp = &s_w[(ky*7 + kx)*32];
            #pragma unroll
            for (int c8 = 0; c8 < 4; ++c8) {
                bf16x8 xv = xp[c8];
                #pragma unroll
                for (int jj = 0; jj < 8; ++jj)
                    acc += (float)xv[jj]*wp[c8*8 + jj];
            }
        }
    }
    out[gidx] = 1.f/(1.f + __expf(-acc));
}

// ======================================================================
// host
// ======================================================================
extern "C" void kernel_launch(void* const* d_in, const int* in_sizes, int n_in,
                              void* d_out, int out_size, void* d_ws, size_t ws_size,
                              hipStream_t stream) {
    const float* features = (const float*)d_in[0];
    const int*   src      = (const int*)  d_in[1];
    const int*   dst      = (const int*)  d_in[2];
    const int*   etypes   = (const int*)  d_in[3];
    const float* norm     = (const float*)d_in[4];
    const float* bases0 = (const float*)d_in[5];
    const float* comp0  = (const float*)d_in[6];
    const float* loop0  = (const float*)d_in[7];
    const float* bias0  = (const float*)d_in[8];
    const float* bases1 = (const float*)d_in[9];
    const float* comp1  = (const float*)d_in[10];
    const float* loop1  = (const float*)d_in[11];
    const float* bias1  = (const float*)d_in[12];
    const float* bases2 = (const float*)d_in[13];
    const float* comp2  = (const float*)d_in[14];
    const float* loop2  = (const float*)d_in[15];
    const float* bias2  = (const float*)d_in[16];
    const float* conv_w = (const float*)d_in[17];
    const float* conv_b = (const float*)d_in[18];
    float* out = (float*)d_out;

    // ---- workspace carve-up (float units, 16B-aligned chunks) ----
    float* ws = (float*)d_ws;
    size_t off = 0;
    auto pad4 = [](size_t v){ return (v + 3) & ~(size_t)3; };
    __bf16* Wt0   = (__bf16*)(ws + off); off += (size_t)R_REL*64*32/2;
    __bf16* Wt1   = (__bf16*)(ws + off); off += (size_t)R_REL*64*64/2;
    __bf16* Wt2   = (__bf16*)(ws + off); off += (size_t)R_REL*32*64/2;
    __bf16* lt0   = (__bf16*)(ws + off); off += (size_t)64*32/2;
    __bf16* lt1   = (__bf16*)(ws + off); off += (size_t)64*64/2;
    __bf16* lt2   = (__bf16*)(ws + off); off += (size_t)32*64/2;
    __bf16* h1    = (__bf16*)(ws + off); off += (size_t)N_NODES*64/2;
    __bf16* h2    = (__bf16*)(ws + off); off += (size_t)N_NODES*64/2;
    __bf16* lg    = (__bf16*)(ws + off); off += (size_t)N_NODES*32/2;
    int* rowptr   = (int*)(ws + off); off += pad4((size_t)N_NODES + 4);
    int* rowptr2  = (int*)(ws + off); off += pad4((size_t)N_NODES*9 + 16);
    int* deg2     = (int*)(ws + off); off += (size_t)N_NODES*R_REL;
    int* cursor2  = (int*)(ws + off); off += (size_t)N_NODES*R_REL;
    int* deg      = (int*)(ws + off); off += (size_t)N_NODES;
    int* bsum     = (int*)(ws + off); off += 512;
    int* pidx2    = (int*)(ws + off); off += (size_t)E_EDGES;
    float* pnorm2 = ws + off;          off += (size_t)E_EDGES;
    size_t base_bytes = off*sizeof(float);
    __bf16* xbuf  = (__bf16*)(ws + off); off += (size_t)N_NODES*R_REL*64/2;  // 118 MB
    size_t needed_main = off*sizeof(float);
    (void)base_bytes;

    const int ebl = (E_EDGES + 255)/256;

    // ---- weight prep (transposed bf16) ----
    k_wcomp_t<<<(R_REL*32*64 + 255)/256, 256, 0, stream>>>(bases0, comp0, Wt0, 32, 64);
    k_wcomp_t<<<(R_REL*64*64 + 255)/256, 256, 0, stream>>>(bases1, comp1, Wt1, 64, 64);
    k_wcomp_t<<<(R_REL*64*32 + 255)/256, 256, 0, stream>>>(bases2, comp2, Wt2, 64, 32);
    k_loop_t<<<(32*64 + 255)/256, 256, 0, stream>>>(loop0, lt0, 32, 64);
    k_loop_t<<<(64*64 + 255)/256, 256, 0, stream>>>(loop1, lt1, 64, 64);
    k_loop_t<<<(64*32 + 255)/256, 256, 0, stream>>>(loop2, lt2, 64, 32);

    // ---- (dst,etype)-binned CSR ----
    hipMemsetAsync(deg2, 0, (size_t)N_NODES*R_REL*sizeof(int), stream);
    k_deg2   <<<ebl, 256, 0, stream>>>(dst, etypes, deg2);
    k_degsum <<<SCAN_BLOCKS, 256, 0, stream>>>(deg2, deg);
    k_scan1  <<<SCAN_BLOCKS, 256, 0, stream>>>(deg, rowptr, bsum);
    k_scan2  <<<1, 512, 0, stream>>>(bsum, rowptr);
    k_scan3  <<<SCAN_BLOCKS, 256, 0, stream>>>(rowptr, bsum);
    k_rowptr2<<<SCAN_BLOCKS, 256, 0, stream>>>(rowptr, deg2, rowptr2, cursor2);
    k_scatter_direct<<<ebl, 256, 0, stream>>>(src, dst, etypes, norm, cursor2, pidx2, pnorm2);

    const int NROWT = N_NODES/64;   // 1800
    const int NAGG  = N_NODES*4/256; // 1800

    if (ws_size >= needed_main) {
        // ========== main path: aggregate -> grouped GEMM ==========
        // layer 0: 32 -> 64 (features f32)
        k_agg<32,1><<<NAGG, 256, 0, stream>>>(features, rowptr2, pidx2, pnorm2, xbuf);
        k_ggemm<32,64,0,1><<<NROWT, 256, 0, stream>>>(xbuf, features, Wt0, lt0, bias0, h1);
        // layer 1: 64 -> 64
        k_agg<64,0><<<NAGG, 256, 0, stream>>>(h1, rowptr2, pidx2, pnorm2, xbuf);
        k_ggemm<64,64,0,0><<<NROWT, 256, 0, stream>>>(xbuf, h1, Wt1, lt1, bias1, h2);
        // layer 2: 64 -> 32, sigmoid
        k_agg<64,0><<<NAGG, 256, 0, stream>>>(h2, rowptr2, pidx2, pnorm2, xbuf);
        k_ggemm<64,32,1,0><<<NROWT, 256, 0, stream>>>(xbuf, h2, Wt2, lt2, bias2, lg);
    } else {
        // ========== fallback: round-5 fused path ==========
        k_fused_mfma<32,64,0,1><<<NROWT, 256, 0, stream>>>(features, Wt0, lt0, bias0,
                                                           rowptr2, pidx2, pnorm2, h1);
        k_fused_mfma<64,64,0,0><<<NROWT, 256, 0, stream>>>(h1, Wt1, lt1, bias1,
                                                           rowptr2, pidx2, pnorm2, h2);
        k_fused_mfma<64,32,1,0><<<NROWT, 256, 0, stream>>>(h2, Wt2, lt2, bias2,
                                                           rowptr2, pidx2, pnorm2, lg);
    }

    // ---- decoder ----
    k_convt<<<(B_GR*IWID*IWID + 255)/256, 256, 0, stream>>>(lg, conv_w, conv_b, out);
}

// Round 10
// 499.757 us; speedup vs baseline: 2.2316x; 1.0398x over previous
//
#include <hip/hip_runtime.h>
#include <hip/hip_bf16.h>

// Problem constants (match reference)
#define B_GR   128
#define GWID   30
#define IWID   90
#define C_IN   32
#define R_REL  8
#define NBAS   4
#define N_NODES (B_GR*GWID*GWID)   // 115200
#define E_EDGES (N_NODES*8)        // 921600
#define NEG_SLOPE 0.01f

#define SCAN_BLOCKS (N_NODES/256)  // 450

typedef __attribute__((ext_vector_type(8))) __bf16 bf16x8;
typedef __attribute__((ext_vector_type(4))) float f32x4;

// ======================================================================
// Weight prep (main): Bt[b][c][k] = bf16(bases[b][k][c])  (B^T per base)
//                     loopt[c][k] = bf16(loopw[k][c])
// ======================================================================
__global__ void k_bases_t(const float* __restrict__ bases, __bf16* __restrict__ Bt,
                          int din, int dout) {
    int idx = blockIdx.x*256 + threadIdx.x;
    int tot = NBAS*din*dout;
    if (idx >= tot) return;
    int b = idx/(dout*din), rem = idx%(dout*din);
    int c = rem/din, k = rem%din;
    Bt[idx] = (__bf16)bases[((size_t)b*din + k)*dout + c];
}
__global__ void k_loop_t(const float* __restrict__ loopw, __bf16* __restrict__ loopt,
                         int din, int dout) {
    int idx = blockIdx.x*256 + threadIdx.x;
    if (idx >= din*dout) return;
    int c = idx/din, k = idx%din;
    loopt[idx] = (__bf16)loopw[(size_t)k*dout + c];
}
// Weight prep (fallback): Wt[r][c][k] = bf16(sum_b comp[r,b]*bases[b,k,c])
__global__ void k_wcomp_t(const float* __restrict__ bases, const float* __restrict__ comp,
                          __bf16* __restrict__ Wt, int din, int dout) {
    int idx = blockIdx.x*256 + threadIdx.x;
    int tot = R_REL*din*dout;
    if (idx >= tot) return;
    int r = idx/(dout*din), rem = idx%(dout*din);
    int c = rem/din, k = rem%din;
    float acc = 0.f;
    #pragma unroll
    for (int b = 0; b < NBAS; ++b)
        acc += comp[r*NBAS + b]*bases[((size_t)b*din + k)*dout + c];
    Wt[idx] = (__bf16)acc;
}

// ======================================================================
// Scan kernels (exclusive scan over N_NODES ints)
// ======================================================================
__global__ __launch_bounds__(256) void k_scan1(const int* __restrict__ deg,
                                               int* __restrict__ rowptr,
                                               int* __restrict__ bsum) {
    __shared__ int s[256], s2[256];
    const int tid = threadIdx.x, gid = blockIdx.x*256 + tid;
    int v = deg[gid];
    s[tid] = v;
    __syncthreads();
    int* cur = s; int* nxt = s2;
    for (int d = 1; d < 256; d <<= 1) {
        int val = cur[tid];
        if (tid >= d) val += cur[tid - d];
        nxt[tid] = val;
        __syncthreads();
        int* t = cur; cur = nxt; nxt = t;
    }
    rowptr[gid] = cur[tid] - v;
    if (tid == 255) bsum[blockIdx.x] = cur[255];
}
__global__ __launch_bounds__(512) void k_scan2(int* __restrict__ bsum, int* __restrict__ rowptr) {
    __shared__ int s[512], s2[512];
    const int tid = threadIdx.x;
    int v = (tid < SCAN_BLOCKS) ? bsum[tid] : 0;
    s[tid] = v;
    __syncthreads();
    int* cur = s; int* nxt = s2;
    for (int d = 1; d < 512; d <<= 1) {
        int val = cur[tid];
        if (tid >= d) val += cur[tid - d];
        nxt[tid] = val;
        __syncthreads();
        int* t = cur; cur = nxt; nxt = t;
    }
    if (tid < SCAN_BLOCKS) bsum[tid] = cur[tid] - v;   // exclusive
    if (tid == 0) rowptr[N_NODES] = E_EDGES;
}
__global__ void k_scan3(int* __restrict__ rowptr, const int* __restrict__ bsum,
                        int* __restrict__ cursor) {
    int gid = blockIdx.x*256 + threadIdx.x;
    int v = rowptr[gid] + bsum[blockIdx.x];
    rowptr[gid] = v;
    cursor[gid] = v;
}
__global__ void k_reseed(const int* __restrict__ rowptr, int* __restrict__ cursor) {
    int gid = blockIdx.x*256 + threadIdx.x;
    cursor[gid] = rowptr[gid];
}

// ======================================================================
// Main-path prep: plain dst-CSR + per-edge basis weights pw4 = norm*comp[et]
// ======================================================================
__global__ void k_deg(const int* __restrict__ dst, int* __restrict__ deg) {
    int e = blockIdx.x*256 + threadIdx.x;
    if (e < E_EDGES) atomicAdd(&deg[dst[e]], 1);
}
__global__ void k_scatter_pw(const int* __restrict__ src, const int* __restrict__ dst,
                             const int* __restrict__ et, const float* __restrict__ norm,
                             const float* __restrict__ comp, int* __restrict__ cursor,
                             int* __restrict__ pidx2, float4* __restrict__ pw4) {
    int e = blockIdx.x*256 + threadIdx.x;
    if (e < E_EDGES) {
        int pos = atomicAdd(&cursor[dst[e]], 1);
        pidx2[pos] = src[e];
        float nm = norm[e];
        const float* cr = comp + et[e]*NBAS;
        pw4[pos] = make_float4(nm*cr[0], nm*cr[1], nm*cr[2], nm*cr[3]);
    }
}

// ======================================================================
// Pass A (main): basis aggregation.
//   y[n][b*DIN + c] = sum_{e in in(n)} pw4[e][b] * h[src_e][c]
// TPN = DIN/8 threads per node, 8 cols each. One walk of the node's full
// CSR segment. f32 reg accum -> bf16 store. 4 outputs per h-load.
// ======================================================================
template<int DIN, int IN_F32>
__global__ __launch_bounds__(256) void k_aggb(
        const void* __restrict__ hin, const int* __restrict__ rowptr,
        const int* __restrict__ pidx2, const float4* __restrict__ pw4,
        __bf16* __restrict__ y) {
    constexpr int TPN = DIN/8;
    const int t = blockIdx.x*256 + threadIdx.x;
    const int n = t / TPN;
    const int cg = t % TPN;
    if (n >= N_NODES) return;
    const int c0 = cg*8;
    float acc[NBAS][8];
    #pragma unroll
    for (int b = 0; b < NBAS; ++b)
        #pragma unroll
        for (int c = 0; c < 8; ++c) acc[b][c] = 0.f;

    const int jb = rowptr[n], je = rowptr[n+1];
    for (int j = jb; j < je; ++j) {
        const int p = pidx2[j];
        const float4 w = pw4[j];
        float hv[8];
        if (IN_F32) {
            const float* hp = (const float*)hin + (size_t)p*DIN + c0;
            float4 a = *(const float4*)hp;
            float4 bb = *(const float4*)(hp + 4);
            hv[0]=a.x; hv[1]=a.y; hv[2]=a.z; hv[3]=a.w;
            hv[4]=bb.x; hv[5]=bb.y; hv[6]=bb.z; hv[7]=bb.w;
        } else {
            bf16x8 v = *(const bf16x8*)((const __bf16*)hin + (size_t)p*DIN + c0);
            #pragma unroll
            for (int jj = 0; jj < 8; ++jj) hv[jj] = (float)v[jj];
        }
        #pragma unroll
        for (int c = 0; c < 8; ++c) {
            acc[0][c] += w.x*hv[c];
            acc[1][c] += w.y*hv[c];
            acc[2][c] += w.z*hv[c];
            acc[3][c] += w.w*hv[c];
        }
    }
    __bf16* yrow = y + (size_t)n*(NBAS*DIN) + c0;
    #pragma unroll
    for (int b = 0; b < NBAS; ++b) {
        bf16x8 o;
        #pragma unroll
        for (int c = 0; c < 8; ++c) o[c] = (__bf16)acc[b][c];
        *(bf16x8*)(yrow + (size_t)b*DIN) = o;
    }
}

// ======================================================================
// Pass B (main): basis GEMM.
//   hout[n] = act( sum_b y[n][b] @ B_b + h[n] @ loopw + bias )
// Wave owns 32 rows (2 sub-tiles of 16 sharing B-fragments).
// Lane l: m=l&15, g=l>>4. A: row, cols ks*32+g*8. D: row g*4+ri, col nf*16+m.
// ======================================================================
template<int DIN, int DOUT, int ACT, int IN_F32>
__global__ __launch_bounds__(256) void k_gemmy(
        const __bf16* __restrict__ y, const void* __restrict__ hin,
        const __bf16* __restrict__ Bt, const __bf16* __restrict__ loopt,
        const float* __restrict__ bias, __bf16* __restrict__ hout) {
    constexpr int KS = DIN/32;
    constexpr int NF = DOUT/16;
    const int tid = threadIdx.x;
    const int w = tid >> 6, l = tid & 63;
    const int m = l & 15, g = l >> 4;
    const int nb = blockIdx.x*128 + w*32;

    f32x4 acc0[NF], acc1[NF];
    #pragma unroll
    for (int nf = 0; nf < NF; ++nf) {
        acc0[nf] = (f32x4){0.f,0.f,0.f,0.f};
        acc1[nf] = (f32x4){0.f,0.f,0.f,0.f};
    }

    const __bf16* y0 = y + (size_t)(nb + m)*(NBAS*DIN);
    const __bf16* y1 = y + (size_t)(nb + 16 + m)*(NBAS*DIN);
    #pragma unroll
    for (int b = 0; b < NBAS; ++b) {
        #pragma unroll
        for (int ks = 0; ks < KS; ++ks) {
            bf16x8 fa0 = *(const bf16x8*)(y0 + (size_t)b*DIN + ks*32 + g*8);
            bf16x8 fa1 = *(const bf16x8*)(y1 + (size_t)b*DIN + ks*32 + g*8);
            #pragma unroll
            for (int nf = 0; nf < NF; ++nf) {
                bf16x8 fb = *(const bf16x8*)(Bt + ((size_t)b*DOUT + nf*16 + m)*DIN
                                             + ks*32 + g*8);
                acc0[nf] = __builtin_amdgcn_mfma_f32_16x16x32_bf16(fa0, fb, acc0[nf], 0, 0, 0);
                acc1[nf] = __builtin_amdgcn_mfma_f32_16x16x32_bf16(fa1, fb, acc1[nf], 0, 0, 0);
            }
        }
    }
    // self-loop
    #pragma unroll
    for (int ks = 0; ks < KS; ++ks) {
        bf16x8 fa0, fa1;
        if (IN_F32) {
            const float* hp0 = (const float*)hin + (size_t)(nb + m)*DIN + ks*32 + g*8;
            const float* hp1 = (const float*)hin + (size_t)(nb + 16 + m)*DIN + ks*32 + g*8;
            float4 a0 = *(const float4*)hp0, a1 = *(const float4*)(hp0 + 4);
            float4 b0 = *(const float4*)hp1, b1 = *(const float4*)(hp1 + 4);
            fa0[0]=(__bf16)a0.x; fa0[1]=(__bf16)a0.y; fa0[2]=(__bf16)a0.z; fa0[3]=(__bf16)a0.w;
            fa0[4]=(__bf16)a1.x; fa0[5]=(__bf16)a1.y; fa0[6]=(__bf16)a1.z; fa0[7]=(__bf16)a1.w;
            fa1[0]=(__bf16)b0.x; fa1[1]=(__bf16)b0.y; fa1[2]=(__bf16)b0.z; fa1[3]=(__bf16)b0.w;
            fa1[4]=(__bf16)b1.x; fa1[5]=(__bf16)b1.y; fa1[6]=(__bf16)b1.z; fa1[7]=(__bf16)b1.w;
        } else {
            fa0 = *(const bf16x8*)((const __bf16*)hin + (size_t)(nb + m)*DIN + ks*32 + g*8);
            fa1 = *(const bf16x8*)((const __bf16*)hin + (size_t)(nb + 16 + m)*DIN + ks*32 + g*8);
        }
        #pragma unroll
        for (int nf = 0; nf < NF; ++nf) {
            bf16x8 fb = *(const bf16x8*)(loopt + (size_t)(nf*16 + m)*DIN + ks*32 + g*8);
            acc0[nf] = __builtin_amdgcn_mfma_f32_16x16x32_bf16(fa0, fb, acc0[nf], 0, 0, 0);
            acc1[nf] = __builtin_amdgcn_mfma_f32_16x16x32_bf16(fa1, fb, acc1[nf], 0, 0, 0);
        }
    }
    // epilogue
    #pragma unroll
    for (int s = 0; s < 2; ++s) {
        #pragma unroll
        for (int nf = 0; nf < NF; ++nf) {
            const int col = nf*16 + m;
            const float bv = bias[col];
            f32x4 a = s ? acc1[nf] : acc0[nf];
            #pragma unroll
            for (int ri = 0; ri < 4; ++ri) {
                const int orow = nb + s*16 + g*4 + ri;
                float v = a[ri] + bv;
                if (ACT == 0) v = (v >= 0.f) ? v : NEG_SLOPE*v;
                else          v = 1.f/(1.f + __expf(-v));
                hout[(size_t)orow*DOUT + col] = (__bf16)v;
            }
        }
    }
}

// ======================================================================
// FALLBACK prep: (dst,etype)-binned CSR
// ======================================================================
__global__ void k_deg2(const int* __restrict__ dst, const int* __restrict__ et,
                       int* __restrict__ deg2) {
    int e = blockIdx.x*256 + threadIdx.x;
    if (e < E_EDGES) atomicAdd(&deg2[dst[e]*R_REL + et[e]], 1);
}
__global__ void k_degsum(const int* __restrict__ deg2, int* __restrict__ deg) {
    int n = blockIdx.x*256 + threadIdx.x;
    if (n >= N_NODES) return;
    int s = 0;
    #pragma unroll
    for (int r = 0; r < R_REL; ++r) s += deg2[n*R_REL + r];
    deg[n] = s;
}
__global__ void k_rowptr2(const int* __restrict__ rowptr, const int* __restrict__ deg2,
                          int* __restrict__ rowptr2, int* __restrict__ cursor2) {
    int n = blockIdx.x*256 + threadIdx.x;
    if (n >= N_NODES) return;
    int base = rowptr[n];
    #pragma unroll
    for (int r = 0; r < R_REL; ++r) {
        rowptr2[n*9 + r] = base;
        cursor2[n*R_REL + r] = base;
        base += deg2[n*R_REL + r];
    }
    rowptr2[n*9 + 8] = base;
}
__global__ void k_scatter_direct(const int* __restrict__ src, const int* __restrict__ dst,
                                 const int* __restrict__ et, const float* __restrict__ norm,
                                 int* __restrict__ cursor2, int* __restrict__ pidx2,
                                 float* __restrict__ pnorm2) {
    int e = blockIdx.x*256 + threadIdx.x;
    if (e < E_EDGES) {
        int pos = atomicAdd(&cursor2[dst[e]*R_REL + et[e]], 1);
        pidx2[pos]  = src[e];
        pnorm2[pos] = norm[e];
    }
}

// ======================================================================
// FALLBACK: round-5 fused kernel (per-lane gather + MFMA)
// ======================================================================
template<int DIN, int DOUT, int ACT, int IN_F32>
__global__ __launch_bounds__(256) void k_fused_mfma(
        const void* __restrict__ hin, const __bf16* __restrict__ Wt,
        const __bf16* __restrict__ loopt, const float* __restrict__ bias,
        const int* __restrict__ rowptr2, const int* __restrict__ pidx2,
        const float* __restrict__ pnorm2, __bf16* __restrict__ hout) {
    constexpr int KS = DIN/32;
    constexpr int NF = DOUT/16;
    const int tid = threadIdx.x;
    const int w = tid >> 6;
    const int l = tid & 63;
    const int m = l & 15, g = l >> 4;
    const int node0 = blockIdx.x*64 + w*16;
    const int node = node0 + m;

    f32x4 acc[NF];
    #pragma unroll
    for (int nf = 0; nf < NF; ++nf) acc[nf] = (f32x4){0.f,0.f,0.f,0.f};

    for (int r = 0; r < 9; ++r) {
        float ka[KS][8];
        #pragma unroll
        for (int ks = 0; ks < KS; ++ks)
            #pragma unroll
            for (int j = 0; j < 8; ++j) ka[ks][j] = 0.f;

        if (r < R_REL) {
            const int jb = rowptr2[node*9 + r];
            const int je = rowptr2[node*9 + r + 1];
            for (int j = jb; j < je; ++j) {
                const int p = pidx2[j];
                const float nm = pnorm2[j];
                if (IN_F32) {
                    const float* hp = (const float*)hin + (size_t)p*DIN + g*8;
                    #pragma unroll
                    for (int ks = 0; ks < KS; ++ks) {
                        float4 v0 = *(const float4*)(hp + ks*32);
                        float4 v1 = *(const float4*)(hp + ks*32 + 4);
                        ka[ks][0] += nm*v0.x; ka[ks][1] += nm*v0.y;
                        ka[ks][2] += nm*v0.z; ka[ks][3] += nm*v0.w;
                        ka[ks][4] += nm*v1.x; ka[ks][5] += nm*v1.y;
                        ka[ks][6] += nm*v1.z; ka[ks][7] += nm*v1.w;
                    }
                } else {
                    const __bf16* hp = (const __bf16*)hin + (size_t)p*DIN + g*8;
                    #pragma unroll
                    for (int ks = 0; ks < KS; ++ks) {
                        bf16x8 v = *(const bf16x8*)(hp + ks*32);
                        #pragma unroll
                        for (int jj = 0; jj < 8; ++jj) ka[ks][jj] += nm*(float)v[jj];
                    }
                }
            }
        } else {
            if (IN_F32) {
                const float* hp = (const float*)hin + (size_t)node*DIN + g*8;
                #pragma unroll
                for (int ks = 0; ks < KS; ++ks) {
                    float4 v0 = *(const float4*)(hp + ks*32);
                    float4 v1 = *(const float4*)(hp + ks*32 + 4);
                    ka[ks][0] = v0.x; ka[ks][1] = v0.y; ka[ks][2] = v0.z; ka[ks][3] = v0.w;
                    ka[ks][4] = v1.x; ka[ks][5] = v1.y; ka[ks][6] = v1.z; ka[ks][7] = v1.w;
                }
            } else {
                const __bf16* hp = (const __bf16*)hin + (size_t)node*DIN + g*8;
                #pragma unroll
                for (int ks = 0; ks < KS; ++ks) {
                    bf16x8 v = *(const bf16x8*)(hp + ks*32);
                    #pragma unroll
                    for (int jj = 0; jj < 8; ++jj) ka[ks][jj] = (float)v[jj];
                }
            }
        }

        bf16x8 fa[KS];
        #pragma unroll
        for (int ks = 0; ks < KS; ++ks)
            #pragma unroll
            for (int jj = 0; jj < 8; ++jj) fa[ks][jj] = (__bf16)ka[ks][jj];

        const __bf16* Bt = (r < R_REL) ? (Wt + (size_t)r*DOUT*DIN) : loopt;
        #pragma unroll
        for (int ks = 0; ks < KS; ++ks) {
            #pragma unroll
            for (int nf = 0; nf < NF; ++nf) {
                bf16x8 fb = *(const bf16x8*)(Bt + (size_t)(nf*16 + m)*DIN + ks*32 + g*8);
                acc[nf] = __builtin_amdgcn_mfma_f32_16x16x32_bf16(fa[ks], fb, acc[nf], 0, 0, 0);
            }
        }
    }
    #pragma unroll
    for (int nf = 0; nf < NF; ++nf) {
        const int col = nf*16 + m;
        const float bv = bias[col];
        #pragma unroll
        for (int ri = 0; ri < 4; ++ri) {
            const int orow = node0 + g*4 + ri;
            float v = acc[nf][ri] + bv;
            if (ACT == 0) v = (v >= 0.f) ? v : NEG_SLOPE*v;
            else          v = 1.f/(1.f + __expf(-v));
            hout[(size_t)orow*DOUT + col] = (__bf16)v;
        }
    }
}

// ======================================================================
// conv-transpose decoder + sigmoid (bf16 logits input)
// ======================================================================
__global__ __launch_bounds__(256) void k_convt(const __bf16* __restrict__ logits,
        const float* __restrict__ w, const float* __restrict__ cb, float* __restrict__ out) {
    __shared__ float s_w[49*32];
    const int tid = threadIdx.x;
    for (int idx = tid; idx < 49*32; idx += 256) {
        int tap = idx/32, c = idx%32;
        s_w[tap*32 + c] = w[c*49 + tap];
    }
    __syncthreads();
    int gidx = blockIdx.x*256 + tid;
    if (gidx >= B_GR*IWID*IWID) return;
    int b = gidx/(IWID*IWID);
    int rem = gidx%(IWID*IWID);
    int oy = rem/IWID, ox = rem%IWID;

    float acc = cb[0];
    for (int ky = 0; ky < 7; ++ky) {
        int t = oy + 2 - ky;
        if (t < 0 || (t % 3) != 0) continue;
        int iy = t/3; if (iy >= GWID) continue;
        for (int kx = 0; kx < 7; ++kx) {
            int u = ox + 2 - kx;
            if (u < 0 || (u % 3) != 0) continue;
            int ix = u/3; if (ix >= GWID) continue;
            const bf16x8* xp = (const bf16x8*)&logits[(((size_t)b*GWID + iy)*GWID + ix)*32];
            const float* wp = &s_w[(ky*7 + kx)*32];
            #pragma unroll
            for (int c8 = 0; c8 < 4; ++c8) {
                bf16x8 xv = xp[c8];
                #pragma unroll
                for (int jj = 0; jj < 8; ++jj)
                    acc += (float)xv[jj]*wp[c8*8 + jj];
            }
        }
    }
    out[gidx] = 1.f/(1.f + __expf(-acc));
}

// ======================================================================
// host
// ======================================================================
extern "C" void kernel_launch(void* const* d_in, const int* in_sizes, int n_in,
                              void* d_out, int out_size, void* d_ws, size_t ws_size,
                              hipStream_t stream) {
    const float* features = (const float*)d_in[0];
    const int*   src      = (const int*)  d_in[1];
    const int*   dst      = (const int*)  d_in[2];
    const int*   etypes   = (const int*)  d_in[3];
    const float* norm     = (const float*)d_in[4];
    const float* bases0 = (const float*)d_in[5];
    const float* comp0  = (const float*)d_in[6];
    const float* loop0  = (const float*)d_in[7];
    const float* bias0  = (const float*)d_in[8];
    const float* bases1 = (const float*)d_in[9];
    const float* comp1  = (const float*)d_in[10];
    const float* loop1  = (const float*)d_in[11];
    const float* bias1  = (const float*)d_in[12];
    const float* bases2 = (const float*)d_in[13];
    const float* comp2  = (const float*)d_in[14];
    const float* loop2  = (const float*)d_in[15];
    const float* bias2  = (const float*)d_in[16];
    const float* conv_w = (const float*)d_in[17];
    const float* conv_b = (const float*)d_in[18];
    float* out = (float*)d_out;

    const int ebl = (E_EDGES + 255)/256;
    float* ws = (float*)d_ws;
    auto pad4 = [](size_t v){ return (v + 3) & ~(size_t)3; };

    // ---- main-path carve (float units) ----
    size_t off = 0;
    __bf16* Bt0   = (__bf16*)(ws + off); off += (size_t)NBAS*32*64/2;
    __bf16* Bt1   = (__bf16*)(ws + off); off += (size_t)NBAS*64*64/2;
    __bf16* Bt2   = (__bf16*)(ws + off); off += (size_t)NBAS*64*32/2;
    __bf16* lt0   = (__bf16*)(ws + off); off += (size_t)64*32/2;
    __bf16* lt1   = (__bf16*)(ws + off); off += (size_t)64*64/2;
    __bf16* lt2   = (__bf16*)(ws + off); off += (size_t)32*64/2;
    __bf16* h1    = (__bf16*)(ws + off); off += (size_t)N_NODES*64/2;
    __bf16* h2    = (__bf16*)(ws + off); off += (size_t)N_NODES*64/2;
    __bf16* lg    = (__bf16*)(ws + off); off += (size_t)N_NODES*32/2;
    int* rowptr   = (int*)(ws + off); off += pad4((size_t)N_NODES + 4);
    int* deg      = (int*)(ws + off); off += (size_t)N_NODES;    // becomes cursor
    int* bsum     = (int*)(ws + off); off += 512;
    int* pidx2    = (int*)(ws + off); off += (size_t)E_EDGES;
    float4* pw4   = (float4*)(ws + off); off += (size_t)E_EDGES*4;
    __bf16* ybuf  = (__bf16*)(ws + off); off += (size_t)N_NODES*NBAS*64/2;  // 59 MB
    size_t needed_main = off*sizeof(float);

    const int NROWT = N_NODES/64;    // 1800
    const int NROWG = N_NODES/128;   // 900

    if (ws_size >= needed_main) {
        // ================= main path: basis aggregate -> basis GEMM =================
        k_bases_t<<<(NBAS*32*64 + 255)/256, 256, 0, stream>>>(bases0, Bt0, 32, 64);
        k_bases_t<<<(NBAS*64*64 + 255)/256, 256, 0, stream>>>(bases1, Bt1, 64, 64);
        k_bases_t<<<(NBAS*64*32 + 255)/256, 256, 0, stream>>>(bases2, Bt2, 64, 32);
        k_loop_t<<<(32*64 + 255)/256, 256, 0, stream>>>(loop0, lt0, 32, 64);
        k_loop_t<<<(64*64 + 255)/256, 256, 0, stream>>>(loop1, lt1, 64, 64);
        k_loop_t<<<(64*32 + 255)/256, 256, 0, stream>>>(loop2, lt2, 64, 32);

        hipMemsetAsync(deg, 0, (size_t)N_NODES*sizeof(int), stream);
        k_deg  <<<ebl, 256, 0, stream>>>(dst, deg);
        k_scan1<<<SCAN_BLOCKS, 256, 0, stream>>>(deg, rowptr, bsum);
        k_scan2<<<1, 512, 0, stream>>>(bsum, rowptr);
        k_scan3<<<SCAN_BLOCKS, 256, 0, stream>>>(rowptr, bsum, deg);  // rowptr final, cursor seeded

        // layer 0: pw4 from comp0
        k_scatter_pw<<<ebl, 256, 0, stream>>>(src, dst, etypes, norm, comp0,
                                              deg, pidx2, pw4);
        k_aggb<32,1><<<N_NODES*4/256, 256, 0, stream>>>(features, rowptr, pidx2, pw4, ybuf);
        k_gemmy<32,64,0,1><<<NROWG, 256, 0, stream>>>(ybuf, features, Bt0, lt0, bias0, h1);

        // layer 1: reseed cursor, pw4 from comp1
        k_reseed<<<SCAN_BLOCKS, 256, 0, stream>>>(rowptr, deg);
        k_scatter_pw<<<ebl, 256, 0, stream>>>(src, dst, etypes, norm, comp1,
                                              deg, pidx2, pw4);
        k_aggb<64,0><<<N_NODES*8/256, 256, 0, stream>>>(h1, rowptr, pidx2, pw4, ybuf);
        k_gemmy<64,64,0,0><<<NROWG, 256, 0, stream>>>(ybuf, h1, Bt1, lt1, bias1, h2);

        // layer 2: reseed cursor, pw4 from comp2
        k_reseed<<<SCAN_BLOCKS, 256, 0, stream>>>(rowptr, deg);
        k_scatter_pw<<<ebl, 256, 0, stream>>>(src, dst, etypes, norm, comp2,
                                              deg, pidx2, pw4);
        k_aggb<64,0><<<N_NODES*8/256, 256, 0, stream>>>(h2, rowptr, pidx2, pw4, ybuf);
        k_gemmy<64,32,1,0><<<NROWG, 256, 0, stream>>>(ybuf, h2, Bt2, lt2, bias2, lg);
    } else {
        // ================= fallback: round-5 fused path =================
        size_t f = 0;
        __bf16* Wt0   = (__bf16*)(ws + f); f += (size_t)R_REL*64*32/2;
        __bf16* Wt1   = (__bf16*)(ws + f); f += (size_t)R_REL*64*64/2;
        __bf16* Wt2   = (__bf16*)(ws + f); f += (size_t)R_REL*32*64/2;
        __bf16* flt0  = (__bf16*)(ws + f); f += (size_t)64*32/2;
        __bf16* flt1  = (__bf16*)(ws + f); f += (size_t)64*64/2;
        __bf16* flt2  = (__bf16*)(ws + f); f += (size_t)32*64/2;
        __bf16* fh1   = (__bf16*)(ws + f); f += (size_t)N_NODES*64/2;
        __bf16* fh2   = (__bf16*)(ws + f); f += (size_t)N_NODES*64/2;
        __bf16* flg   = (__bf16*)(ws + f); f += (size_t)N_NODES*32/2;
        int* frowptr  = (int*)(ws + f); f += pad4((size_t)N_NODES + 4);
        int* frowptr2 = (int*)(ws + f); f += pad4((size_t)N_NODES*9 + 16);
        int* fdeg2    = (int*)(ws + f); f += (size_t)N_NODES*R_REL;
        int* fcursor2 = (int*)(ws + f); f += (size_t)N_NODES*R_REL;
        int* fdeg     = (int*)(ws + f); f += (size_t)N_NODES;
        int* fbsum    = (int*)(ws + f); f += 512;
        int* fpidx2   = (int*)(ws + f); f += (size_t)E_EDGES;
        float* fpnorm2 = ws + f;        f += (size_t)E_EDGES;

        k_wcomp_t<<<(R_REL*32*64 + 255)/256, 256, 0, stream>>>(bases0, comp0, Wt0, 32, 64);
        k_wcomp_t<<<(R_REL*64*64 + 255)/256, 256, 0, stream>>>(bases1, comp1, Wt1, 64, 64);
        k_wcomp_t<<<(R_REL*64*32 + 255)/256, 256, 0, stream>>>(bases2, comp2, Wt2, 64, 32);
        k_loop_t<<<(32*64 + 255)/256, 256, 0, stream>>>(loop0, flt0, 32, 64);
        k_loop_t<<<(64*64 + 255)/256, 256, 0, stream>>>(loop1, flt1, 64, 64);
        k_loop_t<<<(64*32 + 255)/256, 256, 0, stream>>>(loop2, flt2, 64, 32);

        hipMemsetAsync(fdeg2, 0, (size_t)N_NODES*R_REL*sizeof(int), stream);
        k_deg2   <<<ebl, 256, 0, stream>>>(dst, etypes, fdeg2);
        k_degsum <<<SCAN_BLOCKS, 256, 0, stream>>>(fdeg2, fdeg);
        k_scan1  <<<SCAN_BLOCKS, 256, 0, stream>>>(fdeg, frowptr, fbsum);
        k_scan2  <<<1, 512, 0, stream>>>(fbsum, frowptr);
        k_scan3  <<<SCAN_BLOCKS, 256, 0, stream>>>(frowptr, fbsum, fdeg);
        k_rowptr2<<<SCAN_BLOCKS, 256, 0, stream>>>(frowptr, fdeg2, frowptr2, fcursor2);
        k_scatter_direct<<<ebl, 256, 0, stream>>>(src, dst, etypes, norm, fcursor2,
                                                  fpidx2, fpnorm2);

        k_fused_mfma<32,64,0,1><<<NROWT, 256, 0, stream>>>(features, Wt0, flt0, bias0,
                                                           frowptr2, fpidx2, fpnorm2, fh1);
        k_fused_mfma<64,64,0,0><<<NROWT, 256, 0, stream>>>(fh1, Wt1, flt1, bias1,
                                                           frowptr2, fpidx2, fpnorm2, fh2);
        k_fused_mfma<64,32,1,0><<<NROWT, 256, 0, stream>>>(fh2, Wt2, flt2, bias2,
                                                           frowptr2, fpidx2, fpnorm2, flg);
        lg = flg;
    }

    // ---- decoder ----
    k_convt<<<(B_GR*IWID*IWID + 255)/256, 256, 0, stream>>>(lg, conv_w, conv_b, out);
}

// Round 11
// 344.704 us; speedup vs baseline: 3.2354x; 1.4498x over previous
//
#include <hip/hip_runtime.h>
#include <hip/hip_bf16.h>

// Problem constants (match reference)
#define B_GR   128
#define GWID   30
#define IWID   90
#define C_IN   32
#define R_REL  8
#define NBAS   4
#define N_NODES (B_GR*GWID*GWID)   // 115200
#define E_EDGES (N_NODES*8)        // 921600
#define NEG_SLOPE 0.01f

#define SCAN_BLOCKS (N_NODES/256)  // 450

typedef __attribute__((ext_vector_type(8))) __bf16 bf16x8;
typedef __attribute__((ext_vector_type(4))) float f32x4;

// ======================================================================
// Weight prep: Bt[b][c][k] = bf16(bases[b][k][c])  (B^T per base)
//              loopt[c][k] = bf16(loopw[k][c])
// ======================================================================
__global__ void k_bases_t(const float* __restrict__ bases, __bf16* __restrict__ Bt,
                          int din, int dout) {
    int idx = blockIdx.x*256 + threadIdx.x;
    int tot = NBAS*din*dout;
    if (idx >= tot) return;
    int b = idx/(dout*din), rem = idx%(dout*din);
    int c = rem/din, k = rem%din;
    Bt[idx] = (__bf16)bases[((size_t)b*din + k)*dout + c];
}
__global__ void k_loop_t(const float* __restrict__ loopw, __bf16* __restrict__ loopt,
                         int din, int dout) {
    int idx = blockIdx.x*256 + threadIdx.x;
    if (idx >= din*dout) return;
    int c = idx/din, k = idx%din;
    loopt[idx] = (__bf16)loopw[(size_t)k*dout + c];
}

// ======================================================================
// prep: plain dst-CSR, single scatter with packed (src | et<<24) metadata
// ======================================================================
__global__ void k_deg(const int* __restrict__ dst, int* __restrict__ deg) {
    int e = blockIdx.x*256 + threadIdx.x;
    if (e < E_EDGES) atomicAdd(&deg[dst[e]], 1);
}
__global__ __launch_bounds__(256) void k_scan1(const int* __restrict__ deg,
                                               int* __restrict__ rowptr,
                                               int* __restrict__ bsum) {
    __shared__ int s[256], s2[256];
    const int tid = threadIdx.x, gid = blockIdx.x*256 + tid;
    int v = deg[gid];
    s[tid] = v;
    __syncthreads();
    int* cur = s; int* nxt = s2;
    for (int d = 1; d < 256; d <<= 1) {
        int val = cur[tid];
        if (tid >= d) val += cur[tid - d];
        nxt[tid] = val;
        __syncthreads();
        int* t = cur; cur = nxt; nxt = t;
    }
    rowptr[gid] = cur[tid] - v;
    if (tid == 255) bsum[blockIdx.x] = cur[255];
}
__global__ __launch_bounds__(512) void k_scan2(int* __restrict__ bsum, int* __restrict__ rowptr) {
    __shared__ int s[512], s2[512];
    const int tid = threadIdx.x;
    int v = (tid < SCAN_BLOCKS) ? bsum[tid] : 0;
    s[tid] = v;
    __syncthreads();
    int* cur = s; int* nxt = s2;
    for (int d = 1; d < 512; d <<= 1) {
        int val = cur[tid];
        if (tid >= d) val += cur[tid - d];
        nxt[tid] = val;
        __syncthreads();
        int* t = cur; cur = nxt; nxt = t;
    }
    if (tid < SCAN_BLOCKS) bsum[tid] = cur[tid] - v;   // exclusive
    if (tid == 0) rowptr[N_NODES] = E_EDGES;
}
__global__ void k_scan3(int* __restrict__ rowptr, const int* __restrict__ bsum,
                        int* __restrict__ cursor) {
    int gid = blockIdx.x*256 + threadIdx.x;
    int v = rowptr[gid] + bsum[blockIdx.x];
    rowptr[gid] = v;
    cursor[gid] = v;
}
__global__ void k_scatter_pack(const int* __restrict__ src, const int* __restrict__ dst,
                               const int* __restrict__ et, const float* __restrict__ norm,
                               int* __restrict__ cursor, int* __restrict__ ppack,
                               float* __restrict__ pnorm) {
    int e = blockIdx.x*256 + threadIdx.x;
    if (e < E_EDGES) {
        int pos = atomicAdd(&cursor[dst[e]], 1);
        ppack[pos] = src[e] | (et[e] << 24);
        pnorm[pos] = norm[e];
    }
}

// ======================================================================
// Fused basis RGCN layer (per-wave, no LDS, no barriers):
//   hout[n] = act( sum_b (sum_{e in in(n)} norm*comp[et,b]*h[src]) @ B_b
//                  + h[n]@loopw + bias )
// Wave owns 16 rows. Lane l: m=l&15 (row), g=l>>4 (K-group).
// Gather: ONE walk of node's CSR segment, 4 basis accumulators per h-load.
// Then 4 basis MFMA phases + self-loop phase (layouts verified R5/R10).
// ======================================================================
template<int DIN, int DOUT, int ACT, int IN_F32, int OUT_F32>
__global__ __launch_bounds__(256) void k_fusedb(
        const void* __restrict__ hin, const __bf16* __restrict__ Bt,
        const __bf16* __restrict__ loopt, const float* __restrict__ bias,
        const float* __restrict__ comp, const int* __restrict__ rowptr,
        const int* __restrict__ ppack, const float* __restrict__ pnorm,
        void* __restrict__ hout) {
    constexpr int KS = DIN/32;
    constexpr int NF = DOUT/16;
    const int tid = threadIdx.x;
    const int w = tid >> 6, l = tid & 63;
    const int m = l & 15, g = l >> 4;
    const int nb = blockIdx.x*64 + w*16;
    const int node = nb + m;

    f32x4 acc[NF];
    #pragma unroll
    for (int nf = 0; nf < NF; ++nf) acc[nf] = (f32x4){0.f,0.f,0.f,0.f};

    // ---- gather into 4 basis accumulators ----
    float ka[NBAS][KS][8];
    #pragma unroll
    for (int b = 0; b < NBAS; ++b)
        #pragma unroll
        for (int ks = 0; ks < KS; ++ks)
            #pragma unroll
            for (int c = 0; c < 8; ++c) ka[b][ks][c] = 0.f;

    const int jb = rowptr[node], je = rowptr[node+1];
    for (int j = jb; j < je; ++j) {
        const int pk = ppack[j];
        const float nm = pnorm[j];
        const int p = pk & 0xFFFFFF;
        const int et = pk >> 24;
        const float4 cw = *(const float4*)(comp + et*NBAS);
        const float w0 = nm*cw.x, w1 = nm*cw.y, w2 = nm*cw.z, w3 = nm*cw.w;
        float hv[KS][8];
        if (IN_F32) {
            const float* hp = (const float*)hin + (size_t)p*DIN + g*8;
            #pragma unroll
            for (int ks = 0; ks < KS; ++ks) {
                float4 v0 = *(const float4*)(hp + ks*32);
                float4 v1 = *(const float4*)(hp + ks*32 + 4);
                hv[ks][0]=v0.x; hv[ks][1]=v0.y; hv[ks][2]=v0.z; hv[ks][3]=v0.w;
                hv[ks][4]=v1.x; hv[ks][5]=v1.y; hv[ks][6]=v1.z; hv[ks][7]=v1.w;
            }
        } else {
            const __bf16* hp = (const __bf16*)hin + (size_t)p*DIN + g*8;
            #pragma unroll
            for (int ks = 0; ks < KS; ++ks) {
                bf16x8 v = *(const bf16x8*)(hp + ks*32);
                #pragma unroll
                for (int c = 0; c < 8; ++c) hv[ks][c] = (float)v[c];
            }
        }
        #pragma unroll
        for (int ks = 0; ks < KS; ++ks) {
            #pragma unroll
            for (int c = 0; c < 8; ++c) {
                ka[0][ks][c] += w0*hv[ks][c];
                ka[1][ks][c] += w1*hv[ks][c];
                ka[2][ks][c] += w2*hv[ks][c];
                ka[3][ks][c] += w3*hv[ks][c];
            }
        }
    }

    // ---- 4 basis MFMA phases ----
    #pragma unroll
    for (int b = 0; b < NBAS; ++b) {
        #pragma unroll
        for (int ks = 0; ks < KS; ++ks) {
            bf16x8 fa;
            #pragma unroll
            for (int c = 0; c < 8; ++c) fa[c] = (__bf16)ka[b][ks][c];
            #pragma unroll
            for (int nf = 0; nf < NF; ++nf) {
                bf16x8 fb = *(const bf16x8*)(Bt + ((size_t)b*DOUT + nf*16 + m)*DIN
                                             + ks*32 + g*8);
                acc[nf] = __builtin_amdgcn_mfma_f32_16x16x32_bf16(fa, fb, acc[nf], 0, 0, 0);
            }
        }
    }

    // ---- self-loop phase ----
    #pragma unroll
    for (int ks = 0; ks < KS; ++ks) {
        bf16x8 fa;
        if (IN_F32) {
            const float* hp = (const float*)hin + (size_t)node*DIN + ks*32 + g*8;
            float4 v0 = *(const float4*)hp;
            float4 v1 = *(const float4*)(hp + 4);
            fa[0]=(__bf16)v0.x; fa[1]=(__bf16)v0.y; fa[2]=(__bf16)v0.z; fa[3]=(__bf16)v0.w;
            fa[4]=(__bf16)v1.x; fa[5]=(__bf16)v1.y; fa[6]=(__bf16)v1.z; fa[7]=(__bf16)v1.w;
        } else {
            fa = *(const bf16x8*)((const __bf16*)hin + (size_t)node*DIN + ks*32 + g*8);
        }
        #pragma unroll
        for (int nf = 0; nf < NF; ++nf) {
            bf16x8 fb = *(const bf16x8*)(loopt + (size_t)(nf*16 + m)*DIN + ks*32 + g*8);
            acc[nf] = __builtin_amdgcn_mfma_f32_16x16x32_bf16(fa, fb, acc[nf], 0, 0, 0);
        }
    }

    // ---- epilogue: bias + activation + store ----
    #pragma unroll
    for (int nf = 0; nf < NF; ++nf) {
        const int col = nf*16 + m;
        const float bv = bias[col];
        #pragma unroll
        for (int ri = 0; ri < 4; ++ri) {
            const int orow = nb + g*4 + ri;
            float v = acc[nf][ri] + bv;
            if (ACT == 0) v = (v >= 0.f) ? v : NEG_SLOPE*v;
            else          v = 1.f/(1.f + __expf(-v));
            if (OUT_F32) ((float*)hout)[(size_t)orow*DOUT + col] = v;
            else         ((__bf16*)hout)[(size_t)orow*DOUT + col] = (__bf16)v;
        }
    }
}

// ======================================================================
// conv-transpose decoder + sigmoid, f32 logits, branchless phase taps.
// oy+2 = 3*qy + py;  ky = py + 3*sy (<7);  iy = qy - sy in [0,30)
// ======================================================================
__global__ __launch_bounds__(256) void k_convt_f32(const float* __restrict__ logits,
        const float* __restrict__ w, const float* __restrict__ cb, float* __restrict__ out) {
    __shared__ float s_w[49*32];   // [tap][c]
    const int tid = threadIdx.x;
    for (int idx = tid; idx < 49*32; idx += 256) {
        int tap = idx/32, c = idx%32;
        s_w[tap*32 + c] = w[c*49 + tap];
    }
    __syncthreads();
    int gidx = blockIdx.x*256 + tid;
    if (gidx >= B_GR*IWID*IWID) return;
    int b = gidx/(IWID*IWID);
    int rem = gidx%(IWID*IWID);
    int oy = rem/IWID, ox = rem%IWID;

    const int py = (oy+2)%3, qy = (oy+2)/3;
    const int px = (ox+2)%3, qx = (ox+2)/3;

    float acc = cb[0];
    #pragma unroll
    for (int sy = 0; sy < 3; ++sy) {
        const int ky = py + 3*sy;
        const int iy = qy - sy;
        if (ky > 6 || iy < 0 || iy >= GWID) continue;
        #pragma unroll
        for (int sx = 0; sx < 3; ++sx) {
            const int kx = px + 3*sx;
            const int ix = qx - sx;
            if (kx > 6 || ix < 0 || ix >= GWID) continue;
            const float4* xp = (const float4*)&logits[(((size_t)b*GWID + iy)*GWID + ix)*32];
            const float4* wp = (const float4*)&s_w[(ky*7 + kx)*32];
            #pragma unroll
            for (int c4 = 0; c4 < 8; ++c4) {
                float4 xv = xp[c4], wv = wp[c4];
                acc += xv.x*wv.x + xv.y*wv.y + xv.z*wv.z + xv.w*wv.w;
            }
        }
    }
    out[gidx] = 1.f/(1.f + __expf(-acc));
}

// ======================================================================
// host
// ======================================================================
extern "C" void kernel_launch(void* const* d_in, const int* in_sizes, int n_in,
                              void* d_out, int out_size, void* d_ws, size_t ws_size,
                              hipStream_t stream) {
    const float* features = (const float*)d_in[0];
    const int*   src      = (const int*)  d_in[1];
    const int*   dst      = (const int*)  d_in[2];
    const int*   etypes   = (const int*)  d_in[3];
    const float* norm     = (const float*)d_in[4];
    const float* bases0 = (const float*)d_in[5];
    const float* comp0  = (const float*)d_in[6];
    const float* loop0  = (const float*)d_in[7];
    const float* bias0  = (const float*)d_in[8];
    const float* bases1 = (const float*)d_in[9];
    const float* comp1  = (const float*)d_in[10];
    const float* loop1  = (const float*)d_in[11];
    const float* bias1  = (const float*)d_in[12];
    const float* bases2 = (const float*)d_in[13];
    const float* comp2  = (const float*)d_in[14];
    const float* loop2  = (const float*)d_in[15];
    const float* bias2  = (const float*)d_in[16];
    const float* conv_w = (const float*)d_in[17];
    const float* conv_b = (const float*)d_in[18];
    float* out = (float*)d_out;

    const int ebl = (E_EDGES + 255)/256;
    float* ws = (float*)d_ws;
    auto pad4 = [](size_t v){ return (v + 3) & ~(size_t)3; };

    // ---- workspace carve (float units), total ~52 MB ----
    size_t off = 0;
    __bf16* Bt0   = (__bf16*)(ws + off); off += (size_t)NBAS*32*64/2;
    __bf16* Bt1   = (__bf16*)(ws + off); off += (size_t)NBAS*64*64/2;
    __bf16* Bt2   = (__bf16*)(ws + off); off += (size_t)NBAS*64*32/2;
    __bf16* lt0   = (__bf16*)(ws + off); off += (size_t)64*32/2;
    __bf16* lt1   = (__bf16*)(ws + off); off += (size_t)64*64/2;
    __bf16* lt2   = (__bf16*)(ws + off); off += (size_t)32*64/2;
    __bf16* h1    = (__bf16*)(ws + off); off += (size_t)N_NODES*64/2;
    __bf16* h2    = (__bf16*)(ws + off); off += (size_t)N_NODES*64/2;
    float*  lg    = (float*)(ws + off);  off += (size_t)N_NODES*32;   // f32 logits
    int* rowptr   = (int*)(ws + off); off += pad4((size_t)N_NODES + 4);
    int* deg      = (int*)(ws + off); off += (size_t)N_NODES;   // becomes cursor
    int* bsum     = (int*)(ws + off); off += 512;
    int* ppack    = (int*)(ws + off); off += (size_t)E_EDGES;
    float* pnorm  = ws + off;          off += (size_t)E_EDGES;

    // ---- weight prep (transposed bf16 basis + loop tables) ----
    k_bases_t<<<(NBAS*32*64 + 255)/256, 256, 0, stream>>>(bases0, Bt0, 32, 64);
    k_bases_t<<<(NBAS*64*64 + 255)/256, 256, 0, stream>>>(bases1, Bt1, 64, 64);
    k_bases_t<<<(NBAS*64*32 + 255)/256, 256, 0, stream>>>(bases2, Bt2, 64, 32);
    k_loop_t<<<(32*64 + 255)/256, 256, 0, stream>>>(loop0, lt0, 32, 64);
    k_loop_t<<<(64*64 + 255)/256, 256, 0, stream>>>(loop1, lt1, 64, 64);
    k_loop_t<<<(64*32 + 255)/256, 256, 0, stream>>>(loop2, lt2, 64, 32);

    // ---- dst-CSR + single packed scatter (reused by all 3 layers) ----
    hipMemsetAsync(deg, 0, (size_t)N_NODES*sizeof(int), stream);
    k_deg  <<<ebl, 256, 0, stream>>>(dst, deg);
    k_scan1<<<SCAN_BLOCKS, 256, 0, stream>>>(deg, rowptr, bsum);
    k_scan2<<<1, 512, 0, stream>>>(bsum, rowptr);
    k_scan3<<<SCAN_BLOCKS, 256, 0, stream>>>(rowptr, bsum, deg);
    k_scatter_pack<<<ebl, 256, 0, stream>>>(src, dst, etypes, norm, deg, ppack, pnorm);

    const int NROWT = N_NODES/64;   // 1800

    // ---- 3 fused basis layers ----
    k_fusedb<32,64,0,1,0><<<NROWT, 256, 0, stream>>>(features, Bt0, lt0, bias0, comp0,
                                                     rowptr, ppack, pnorm, h1);
    k_fusedb<64,64,0,0,0><<<NROWT, 256, 0, stream>>>(h1, Bt1, lt1, bias1, comp1,
                                                     rowptr, ppack, pnorm, h2);
    k_fusedb<64,32,1,0,1><<<NROWT, 256, 0, stream>>>(h2, Bt2, lt2, bias2, comp2,
                                                     rowptr, ppack, pnorm, lg);

    // ---- decoder (f32 logits) ----
    k_convt_f32<<<(B_GR*IWID*IWID + 255)/256, 256, 0, stream>>>(lg, conv_w, conv_b, out);
}